// Round 9
// baseline (1149.620 us; speedup 1.0000x reference)
//
#include <hip/hip_runtime.h>

#define T_STEPS 1024
#define B_TOT   512
#define VOCAB   1000
#define EMB     64
#define HID     64
#define GATES   256   // 4*HID

typedef float f4 __attribute__((ext_vector_type(4)));

__device__ __forceinline__ float fast_rcp(float x)  { return __builtin_amdgcn_rcpf(x); }
__device__ __forceinline__ float fast_exp2(float x) { return __builtin_amdgcn_exp2f(x); }

__device__ __forceinline__ float sigmoid_f(float x) {
    return fast_rcp(1.0f + fast_exp2(-1.4426950408889634f * x));
}
__device__ __forceinline__ float tanh_f(float x) {
    float e = fast_exp2(2.8853900817779268f * x);
    return 1.0f - 2.0f * fast_rcp(e + 1.0f);
}

// Broadcast lane `lane`'s h to all lanes as an SGPR (VALU pipe, zero LDS).
__device__ __forceinline__ float bcast(float v, int lane) {
    return __int_as_float(__builtin_amdgcn_readlane(__float_as_int(v), lane));
}

// ---------------------------------------------------------------------------
// Kernel 1: zx table, layout [dir][vocab][unit][gate]:
//   thread j: u=j>>2, g=j&3, source col g*64+u, store at linear j ->
//   recurrent lane u reads one coalesced float4 = its unit's 4 gate zx.
// ---------------------------------------------------------------------------
__global__ __launch_bounds__(256, 4)
void zx_table_kernel(const float* __restrict__ emb,
                     const float* __restrict__ Wx_f, const float* __restrict__ b_f,
                     const float* __restrict__ Wx_b, const float* __restrict__ b_b,
                     float* __restrict__ zx_tab)
{
    const int bid = blockIdx.x;            // 0..1999
    const int dir = bid / VOCAB;
    const int v   = bid - dir * VOCAB;
    const int j   = threadIdx.x;
    const int g   = j & 3;
    const int u   = j >> 2;
    const int col = g * HID + u;

    const float* __restrict__ Wx = dir ? Wx_b : Wx_f;
    const float* __restrict__ bv = dir ? b_b  : b_f;

    __shared__ float4 x4[EMB / 4];
    if (j < EMB / 4) x4[j] = ((const float4*)emb)[v * (EMB / 4) + j];
    __syncthreads();

    float a0 = bv[col], a1 = 0.f, a2 = 0.f, a3 = 0.f;
#pragma unroll
    for (int q = 0; q < EMB / 4; ++q) {
        float4 xv = x4[q];
        a0 = fmaf(xv.x, Wx[(4 * q + 0) * GATES + col], a0);
        a1 = fmaf(xv.y, Wx[(4 * q + 1) * GATES + col], a1);
        a2 = fmaf(xv.z, Wx[(4 * q + 2) * GATES + col], a2);
        a3 = fmaf(xv.w, Wx[(4 * q + 3) * GATES + col], a3);
    }
    zx_tab[(dir * VOCAB + v) * GATES + j] = (a0 + a1) + (a2 + a3);
}

// ---------------------------------------------------------------------------
// Kernel 2: recurrence, fp32, K-SPLIT waves, readlane h-broadcast.
// Block = 128 thr = 2 waves per (dir,row). Lane u owns hidden unit u.
// Wave w sums the k in [32w, 32w+32) half of ALL 4 gate dots:
//   32 v_readlane (h from own registers -> SGPR) + 128 fmaf (SGPR src).
// Exchange: one f4 partial write + one f4 read (parity double-buffered)
// around a SINGLE barrier per step. Both waves then compute the identical
// z = (mine+other)+zx (commutative -> bit-identical), all 4 activations,
// and the c/h update redundantly, so h is in-register for the next step's
// readlanes with no further sync. LDS pipe per wave-step: 2 ops (was ~18).
// ---------------------------------------------------------------------------
__global__ __launch_bounds__(128, 2)
void lstm_rec_kernel(const int* __restrict__ tokens,
                     const float* __restrict__ Wh_f,
                     const float* __restrict__ Wh_b,
                     const float* __restrict__ zx_tab,
                     float* __restrict__ out)
{
    const int bx  = blockIdx.x;        // 0..1023
    const int dir = bx >> 9;
    const int row = bx & 511;
    const int u   = threadIdx.x & 63;  // hidden unit
    const int w   = threadIdx.x >> 6;  // k-half: wave w owns k in [32w,32w+32)

    const float* __restrict__ Wh   = dir ? Wh_b : Wh_f;
    const f4*    __restrict__ zx4  = (const f4*)(zx_tab + dir * (VOCAB * GATES));
    const int*   __restrict__ trow = tokens + row * T_STEPS;

    // 128 weights: wt[g][k'] = Wh[(32w+k')][g*64+u], coalesced loads.
    float wt[4][32];
#pragma unroll
    for (int g = 0; g < 4; ++g)
#pragma unroll
        for (int k = 0; k < 32; ++k)
            wt[g][k] = Wh[(w * 32 + k) * GATES + g * HID + u];

    __shared__ f4 part[2][2][HID];     // [parity][wave][unit] -> 4 gate partials

    float c = 0.0f, h = 0.0f;
    int   par = 0;                     // parity (block-uniform)

    // wave-uniform token chain + zx prefetch (one f4 per lane)
    int tokc = trow[dir ? (T_STEPS - 1) : 0];
    int tokn = trow[dir ? (T_STEPS - 2) : 1];
    f4  zxc  = zx4[tokc * (GATES / 4) + u];

#pragma unroll 1
    for (int t = 0; t < T_STEPS; ++t) {
        // prefetches first: latency hides under the fmaf block
        int t2   = (t + 2 < T_STEPS) ? (t + 2) : (T_STEPS - 1);
        int tokf = trow[dir ? (T_STEPS - 1 - t2) : t2];
        f4  zxn  = zx4[tokn * (GATES / 4) + u];

        if (tokc != 0) {               // block-uniform; padded steps carry state
            // ---- half-dot for all 4 gates: 8 chains (2 per gate) ----
            float a0 = 0.f, a1 = 0.f, a2 = 0.f, a3 = 0.f;   // even-k chains
            float b0 = 0.f, b1 = 0.f, b2 = 0.f, b3 = 0.f;   // odd-k chains
#pragma unroll
            for (int k = 0; k < 32; k += 2) {
                float h0 = bcast(h, w * 32 + k);       // SGPR broadcast
                float h1 = bcast(h, w * 32 + k + 1);
                a0 = fmaf(h0, wt[0][k], a0);
                a1 = fmaf(h0, wt[1][k], a1);
                a2 = fmaf(h0, wt[2][k], a2);
                a3 = fmaf(h0, wt[3][k], a3);
                b0 = fmaf(h1, wt[0][k + 1], b0);
                b1 = fmaf(h1, wt[1][k + 1], b1);
                b2 = fmaf(h1, wt[2][k + 1], b2);
                b3 = fmaf(h1, wt[3][k + 1], b3);
            }
            f4 mine;
            mine.x = a0 + b0; mine.y = a1 + b1;
            mine.z = a2 + b2; mine.w = a3 + b3;
            part[par][w][u] = mine;
            __syncthreads();           // the ONLY barrier per step
            f4 other = part[par][w ^ 1][u];

            // z = (p_own + p_other) + zx: commutative -> bit-identical on
            // both waves -> both h copies stay bit-identical forever.
            float zi = (mine.x + other.x) + zxc.x;
            float zf = (mine.y + other.y) + zxc.y;
            float zg = (mine.z + other.z) + zxc.z;
            float zo = (mine.w + other.w) + zxc.w;

            float ig = sigmoid_f(zi);
            float fg = sigmoid_f(zf);
            float gg = tanh_f(zg);
            float og = sigmoid_f(zo);
            c = fmaf(fg, c, ig * gg);
            h = og * tanh_f(c);
            par ^= 1;
        }

        tokc = tokn; tokn = tokf; zxc = zxn;
    }

    if (w == 0)
        out[row * (2 * HID) + dir * HID + u] = h;
}

extern "C" void kernel_launch(void* const* d_in, const int* in_sizes, int n_in,
                              void* d_out, int out_size, void* d_ws, size_t ws_size,
                              hipStream_t stream) {
    const int*   tokens = (const int*)  d_in[0];
    const float* emb    = (const float*)d_in[1];
    const float* Wx_f   = (const float*)d_in[2];
    const float* Wh_f   = (const float*)d_in[3];
    const float* b_f    = (const float*)d_in[4];
    const float* Wx_b   = (const float*)d_in[5];
    const float* Wh_b   = (const float*)d_in[6];
    const float* b_b    = (const float*)d_in[7];
    float* out = (float*)d_out;

    float* zx_tab = (float*)d_ws;   // 2*1000*256*4 = 1.95 MB of d_ws

    hipLaunchKernelGGL(zx_table_kernel, dim3(2 * VOCAB), dim3(GATES), 0, stream,
                       emb, Wx_f, b_f, Wx_b, b_b, zx_tab);
    hipLaunchKernelGGL(lstm_rec_kernel, dim3(2 * B_TOT), dim3(128), 0, stream,
                       tokens, Wh_f, Wh_b, zx_tab, out);
}

// Round 10
// 1088.547 us; speedup vs baseline: 1.0561x; 1.0561x over previous
//
#include <hip/hip_runtime.h>

#define T_STEPS 1024
#define B_TOT   512
#define VOCAB   1000
#define EMB     64
#define HID     64
#define GATES   256   // 4*HID

typedef float f4 __attribute__((ext_vector_type(4)));
typedef float f2 __attribute__((ext_vector_type(2)));

__device__ __forceinline__ float fast_rcp(float x)  { return __builtin_amdgcn_rcpf(x); }
__device__ __forceinline__ float fast_exp2(float x) { return __builtin_amdgcn_exp2f(x); }

__device__ __forceinline__ float sigmoid_f(float x) {
    return fast_rcp(1.0f + fast_exp2(-1.4426950408889634f * x));
}
__device__ __forceinline__ float tanh_f(float x) {
    float e = fast_exp2(2.8853900817779268f * x);
    return 1.0f - 2.0f * fast_rcp(e + 1.0f);
}

// ---------------------------------------------------------------------------
// Kernel 1: zx table. Layout [dir][vocab][wave][unit][pair]:
//   thread j (0..255): p=j&1, u=(j>>1)&63, w=j>>7, source col=(2w+p)*64+u.
// Recurrent lane (w,u) gathers float2 index tok*128 + w*64 + u.
// ---------------------------------------------------------------------------
__global__ __launch_bounds__(256, 4)
void zx_table_kernel(const float* __restrict__ emb,
                     const float* __restrict__ Wx_f, const float* __restrict__ b_f,
                     const float* __restrict__ Wx_b, const float* __restrict__ b_b,
                     float* __restrict__ zx_tab)
{
    const int bid = blockIdx.x;            // 0..1999
    const int dir = bid / VOCAB;
    const int v   = bid - dir * VOCAB;
    const int j   = threadIdx.x;
    const int p   = j & 1;
    const int u   = (j >> 1) & 63;
    const int w   = j >> 7;
    const int col = (2 * w + p) * HID + u;

    const float* __restrict__ Wx = dir ? Wx_b : Wx_f;
    const float* __restrict__ bv = dir ? b_b  : b_f;

    __shared__ float4 x4[EMB / 4];
    if (j < EMB / 4) x4[j] = ((const float4*)emb)[v * (EMB / 4) + j];
    __syncthreads();

    float a0 = bv[col], a1 = 0.f, a2 = 0.f, a3 = 0.f;
#pragma unroll
    for (int q = 0; q < EMB / 4; ++q) {
        float4 xv = x4[q];
        a0 = fmaf(xv.x, Wx[(4 * q + 0) * GATES + col], a0);
        a1 = fmaf(xv.y, Wx[(4 * q + 1) * GATES + col], a1);
        a2 = fmaf(xv.z, Wx[(4 * q + 2) * GATES + col], a2);
        a3 = fmaf(xv.w, Wx[(4 * q + 3) * GATES + col], a3);
    }
    zx_tab[(dir * VOCAB + v) * GATES + j] = (a0 + a1) + (a2 + a3);
}

// ---------------------------------------------------------------------------
// Kernel 2: recurrence, fp32, TWO independent rows per wave (R=2).
// 512 blocks x 2 waves; block = (dir, row-pair). Wave w owns gates 2w,2w+1
// (same 128 weights serve both rows). Per step, the wave runs rows A and B
// as interleaved independent chains (16 fmaf accumulators), so row B's
// arithmetic fills row A's LDS/barrier latency and vice versa; barriers and
// LDS round-trips amortize over 2 rows. Occupancy is 1 wave/SIMD by design.
// ---------------------------------------------------------------------------
__global__ __launch_bounds__(128, 2)
void lstm_rec_kernel(const int* __restrict__ tokens,
                     const float* __restrict__ Wh_f,
                     const float* __restrict__ Wh_b,
                     const float* __restrict__ zx_tab,
                     float* __restrict__ out)
{
    const int bx   = blockIdx.x;       // 0..511
    const int dir  = bx >> 8;
    const int rp   = bx & 255;
    const int rowA = rp * 2, rowB = rp * 2 + 1;
    const int u    = threadIdx.x & 63; // hidden unit
    const int w    = threadIdx.x >> 6; // gate pair: w=0 -> i,f ; w=1 -> g,o

    const float* __restrict__ Wh    = dir ? Wh_b : Wh_f;
    const f2*    __restrict__ zx2   = (const f2*)(zx_tab + dir * (VOCAB * GATES));
    const int*   __restrict__ trowA = tokens + rowA * T_STEPS;
    const int*   __restrict__ trowB = tokens + rowB * T_STEPS;

    // 128 register-resident weights: gate columns (2w)*64+u and (2w+1)*64+u.
    const int colE = (2 * w) * HID + u;
    const int colO = colE + HID;
    float whE[HID], whO[HID];
#pragma unroll
    for (int k = 0; k < HID; ++k) whE[k] = Wh[k * GATES + colE];
#pragma unroll
    for (int k = 0; k < HID; ++k) whO[k] = Wh[k * GATES + colO];

    __shared__ float hbA[HID], hbB[HID];   // h per row
    __shared__ f2    acA[HID], acB[HID];   // wave1 -> wave0: {g,o} per row

    if (threadIdx.x < HID) hbA[threadIdx.x] = 0.0f;
    else                   hbB[threadIdx.x - HID] = 0.0f;
    float cA = 0.0f, cB = 0.0f;
    __syncthreads();

    // wave-uniform token chains + zx prefetch (float2 per lane per row)
    int tA0 = trowA[dir ? (T_STEPS - 1) : 0];
    int tA1 = trowA[dir ? (T_STEPS - 2) : 1];
    int tB0 = trowB[dir ? (T_STEPS - 1) : 0];
    int tB1 = trowB[dir ? (T_STEPS - 2) : 1];
    f2 zxAc = zx2[tA0 * 128 + w * 64 + u];
    f2 zxBc = zx2[tB0 * 128 + w * 64 + u];

    const f4* __restrict__ hb4A = (const f4*)hbA;
    const f4* __restrict__ hb4B = (const f4*)hbB;

#pragma unroll 1
    for (int t = 0; t < T_STEPS; ++t) {
        // prefetches first: latency hides under the fmaf block
        int t2  = (t + 2 < T_STEPS) ? (t + 2) : (T_STEPS - 1);
        int sp  = dir ? (T_STEPS - 1 - t2) : t2;
        int tA2 = trowA[sp];
        int tB2 = trowB[sp];
        f2 zxAn = zx2[tA1 * 128 + w * 64 + u];
        f2 zxBn = zx2[tB1 * 128 + w * 64 + u];

        // ---- 4 dots (2 gates x 2 rows), 16 independent fmaf chains ----
        float eA0 = zxAc.x, eA1 = 0.f, eA2 = 0.f, eA3 = 0.f;
        float oA0 = zxAc.y, oA1 = 0.f, oA2 = 0.f, oA3 = 0.f;
        float eB0 = zxBc.x, eB1 = 0.f, eB2 = 0.f, eB3 = 0.f;
        float oB0 = zxBc.y, oB1 = 0.f, oB2 = 0.f, oB3 = 0.f;
#pragma unroll
        for (int q = 0; q < HID / 4; ++q) {
            f4 hA = hb4A[q];               // LDS broadcast (uniform addr)
            f4 hB = hb4B[q];
            eA0 = fmaf(hA.x, whE[4 * q + 0], eA0);
            eA1 = fmaf(hA.y, whE[4 * q + 1], eA1);
            eA2 = fmaf(hA.z, whE[4 * q + 2], eA2);
            eA3 = fmaf(hA.w, whE[4 * q + 3], eA3);
            oA0 = fmaf(hA.x, whO[4 * q + 0], oA0);
            oA1 = fmaf(hA.y, whO[4 * q + 1], oA1);
            oA2 = fmaf(hA.z, whO[4 * q + 2], oA2);
            oA3 = fmaf(hA.w, whO[4 * q + 3], oA3);
            eB0 = fmaf(hB.x, whE[4 * q + 0], eB0);
            eB1 = fmaf(hB.y, whE[4 * q + 1], eB1);
            eB2 = fmaf(hB.z, whE[4 * q + 2], eB2);
            eB3 = fmaf(hB.w, whE[4 * q + 3], eB3);
            oB0 = fmaf(hB.x, whO[4 * q + 0], oB0);
            oB1 = fmaf(hB.y, whO[4 * q + 1], oB1);
            oB2 = fmaf(hB.z, whO[4 * q + 2], oB2);
            oB3 = fmaf(hB.w, whO[4 * q + 3], oB3);
        }
        float zEA = (eA0 + eA1) + (eA2 + eA3);
        float zOA = (oA0 + oA1) + (oA2 + oA3);
        float zEB = (eB0 + eB1) + (eB2 + eB3);
        float zOB = (oB0 + oB1) + (oB2 + oB3);

        // ---- own-gate activations (wave-uniform branch, both rows) ----
        float aEA, aOA, aEB, aOB;
        if (w == 0) {                      // i, f
            aEA = sigmoid_f(zEA); aOA = sigmoid_f(zOA);
            aEB = sigmoid_f(zEB); aOB = sigmoid_f(zOB);
        } else {                           // g, o
            aEA = tanh_f(zEA);    aOA = sigmoid_f(zOA);
            aEB = tanh_f(zEB);    aOB = sigmoid_f(zOB);
            f2 gA; gA.x = aEA; gA.y = aOA; acA[u] = gA;
            f2 gB; gB.x = aEB; gB.y = aOB; acB[u] = gB;
        }
        __syncthreads();

        // ---- state updates: wave 0, two independent chains ----
        if (w == 0) {
            f2 goA = acA[u];
            f2 goB = acB[u];
            if (tA0 != 0) {                // Keras mask_zero carry (row A)
                cA = fmaf(aOA, cA, aEA * goA.x);
                hbA[u] = goA.y * tanh_f(cA);
            }
            if (tB0 != 0) {                // row B
                cB = fmaf(aOB, cB, aEB * goB.x);
                hbB[u] = goB.y * tanh_f(cB);
            }
        }
        __syncthreads();

        tA0 = tA1; tA1 = tA2; zxAc = zxAn;
        tB0 = tB1; tB1 = tB2; zxBc = zxBn;
    }

    if (w == 0) {
        out[rowA * (2 * HID) + dir * HID + u] = hbA[u];
        out[rowB * (2 * HID) + dir * HID + u] = hbB[u];
    }
}

extern "C" void kernel_launch(void* const* d_in, const int* in_sizes, int n_in,
                              void* d_out, int out_size, void* d_ws, size_t ws_size,
                              hipStream_t stream) {
    const int*   tokens = (const int*)  d_in[0];
    const float* emb    = (const float*)d_in[1];
    const float* Wx_f   = (const float*)d_in[2];
    const float* Wh_f   = (const float*)d_in[3];
    const float* b_f    = (const float*)d_in[4];
    const float* Wx_b   = (const float*)d_in[5];
    const float* Wh_b   = (const float*)d_in[6];
    const float* b_b    = (const float*)d_in[7];
    float* out = (float*)d_out;

    float* zx_tab = (float*)d_ws;   // 2*1000*256*4 = 1.95 MB of d_ws

    hipLaunchKernelGGL(zx_table_kernel, dim3(2 * VOCAB), dim3(GATES), 0, stream,
                       emb, Wx_f, b_f, Wx_b, b_b, zx_tab);
    hipLaunchKernelGGL(lstm_rec_kernel, dim3(B_TOT), dim3(128), 0, stream,
                       tokens, Wh_f, Wh_b, zx_tab, out);
}

// Round 11
// 928.809 us; speedup vs baseline: 1.2377x; 1.1720x over previous
//
#include <hip/hip_runtime.h>

#define T_STEPS 1024
#define B_TOT   512
#define VOCAB   1000
#define EMB     64
#define HID     64
#define GATES   256   // 4*HID

typedef float f4 __attribute__((ext_vector_type(4)));

__device__ __forceinline__ float fast_rcp(float x)  { return __builtin_amdgcn_rcpf(x); }
__device__ __forceinline__ float fast_exp2(float x) { return __builtin_amdgcn_exp2f(x); }

__device__ __forceinline__ float sigmoid_f(float x) {
    return fast_rcp(1.0f + fast_exp2(-1.4426950408889634f * x));
}
__device__ __forceinline__ float tanh_f(float x) {
    float e = fast_exp2(2.8853900817779268f * x);
    return 1.0f - 2.0f * fast_rcp(e + 1.0f);
}

// ---------------------------------------------------------------------------
// Kernel 1: zx table, layout [dir][vocab][unit][gate]:
//   thread j: u=j>>2, g=j&3, source col g*64+u, store at linear j ->
//   recurrent lane u reads ONE coalesced float4 = its unit's 4 gate zx.
// ---------------------------------------------------------------------------
__global__ __launch_bounds__(256, 4)
void zx_table_kernel(const float* __restrict__ emb,
                     const float* __restrict__ Wx_f, const float* __restrict__ b_f,
                     const float* __restrict__ Wx_b, const float* __restrict__ b_b,
                     float* __restrict__ zx_tab)
{
    const int bid = blockIdx.x;            // 0..1999
    const int dir = bid / VOCAB;
    const int v   = bid - dir * VOCAB;
    const int j   = threadIdx.x;
    const int g   = j & 3;
    const int u   = j >> 2;
    const int col = g * HID + u;

    const float* __restrict__ Wx = dir ? Wx_b : Wx_f;
    const float* __restrict__ bv = dir ? b_b  : b_f;

    __shared__ float4 x4[EMB / 4];
    if (j < EMB / 4) x4[j] = ((const float4*)emb)[v * (EMB / 4) + j];
    __syncthreads();

    float a0 = bv[col], a1 = 0.f, a2 = 0.f, a3 = 0.f;
#pragma unroll
    for (int q = 0; q < EMB / 4; ++q) {
        float4 xv = x4[q];
        a0 = fmaf(xv.x, Wx[(4 * q + 0) * GATES + col], a0);
        a1 = fmaf(xv.y, Wx[(4 * q + 1) * GATES + col], a1);
        a2 = fmaf(xv.z, Wx[(4 * q + 2) * GATES + col], a2);
        a3 = fmaf(xv.w, Wx[(4 * q + 3) * GATES + col], a3);
    }
    zx_tab[(dir * VOCAB + v) * GATES + j] = (a0 + a1) + (a2 + a3);
}

// ---------------------------------------------------------------------------
// Kernel 2: recurrence, fp32, ONE WAVE PER ROW — zero barriers.
// 1024 blocks x 64 threads = 1 wave/SIMD chip-wide. Lane u owns hidden unit
// u: all 4 gate columns = 256 fp32 weights per lane. At 1 wave/SIMD the
// unified VGPR+AGPR file (~512 regs/wave) holds them; the allocator parks
// loop-carried arrays in AGPRs which VALU sources directly at zero cost
// (established R4/R6: "v"-pinning ADDED copies and regressed).
// Per step: ds_write h -> 16 uniform ds_read_b128 -> 256 fmaf (8 indep
// chains) -> 4 activations + c/h update, all lane-local. The only
// synchronization is same-wave lgkmcnt ordering on the 256-byte hbuf.
// Critical path ~720 cyc/step vs R4's 1630 (2 barriers + coupled waves).
// ---------------------------------------------------------------------------
__global__ __launch_bounds__(64) __attribute__((amdgpu_waves_per_eu(1)))
void lstm_rec_kernel(const int* __restrict__ tokens,
                     const float* __restrict__ Wh_f,
                     const float* __restrict__ Wh_b,
                     const float* __restrict__ zx_tab,
                     float* __restrict__ out)
{
    const int bx  = blockIdx.x;        // 0..1023
    const int dir = bx >> 9;
    const int row = bx & 511;
    const int u   = threadIdx.x;       // hidden unit 0..63

    const float* __restrict__ Wh   = dir ? Wh_b : Wh_f;
    const f4*    __restrict__ zx4  = (const f4*)(zx_tab + dir * (VOCAB * GATES));
    const int*   __restrict__ trow = tokens + row * T_STEPS;

    // 256 register-resident fp32 weights (VGPR+AGPR unified file).
    float wt0[HID], wt1[HID], wt2[HID], wt3[HID];
#pragma unroll
    for (int k = 0; k < HID; ++k) wt0[k] = Wh[k * GATES + 0 * HID + u];
#pragma unroll
    for (int k = 0; k < HID; ++k) wt1[k] = Wh[k * GATES + 1 * HID + u];
#pragma unroll
    for (int k = 0; k < HID; ++k) wt2[k] = Wh[k * GATES + 2 * HID + u];
#pragma unroll
    for (int k = 0; k < HID; ++k) wt3[k] = Wh[k * GATES + 3 * HID + u];

    __shared__ f4 hb4[HID / 4];        // h broadcast, 256 B, f4-aligned
    float* hbuf = (float*)hb4;
    hbuf[u] = 0.0f;
    float c = 0.0f, h = 0.0f;

    // wave-uniform token chain + zx prefetch (one f4 per lane)
    int tokc = trow[dir ? (T_STEPS - 1) : 0];
    int tokn = trow[dir ? (T_STEPS - 2) : 1];
    f4  zxc  = zx4[tokc * (GATES / 4) + u];

#pragma unroll 1
    for (int t = 0; t < T_STEPS; ++t) {
        // prefetches first: latency hides under the fmaf block
        int t2   = (t + 2 < T_STEPS) ? (t + 2) : (T_STEPS - 1);
        int tokf = trow[dir ? (T_STEPS - 1 - t2) : t2];
        f4  zxn  = zx4[tokn * (GATES / 4) + u];

        // ---- 4 gate dots over h: 8 independent chains, 256 fmaf ----
        float a0 = zxc.x, b0 = 0.f;
        float a1 = zxc.y, b1 = 0.f;
        float a2 = zxc.z, b2 = 0.f;
        float a3 = zxc.w, b3 = 0.f;
#pragma unroll
        for (int q = 0; q < HID / 4; ++q) {
            f4 hv = hb4[q];            // uniform-address LDS broadcast
            a0 = fmaf(hv.x, wt0[4 * q + 0], a0);
            b0 = fmaf(hv.y, wt0[4 * q + 1], b0);
            a0 = fmaf(hv.z, wt0[4 * q + 2], a0);
            b0 = fmaf(hv.w, wt0[4 * q + 3], b0);
            a1 = fmaf(hv.x, wt1[4 * q + 0], a1);
            b1 = fmaf(hv.y, wt1[4 * q + 1], b1);
            a1 = fmaf(hv.z, wt1[4 * q + 2], a1);
            b1 = fmaf(hv.w, wt1[4 * q + 3], b1);
            a2 = fmaf(hv.x, wt2[4 * q + 0], a2);
            b2 = fmaf(hv.y, wt2[4 * q + 1], b2);
            a2 = fmaf(hv.z, wt2[4 * q + 2], a2);
            b2 = fmaf(hv.w, wt2[4 * q + 3], b2);
            a3 = fmaf(hv.x, wt3[4 * q + 0], a3);
            b3 = fmaf(hv.y, wt3[4 * q + 1], b3);
            a3 = fmaf(hv.z, wt3[4 * q + 2], a3);
            b3 = fmaf(hv.w, wt3[4 * q + 3], b3);
        }

        // ---- gates + state update (lane-local; uniform mask branch) ----
        if (tokc != 0) {               // Keras mask_zero: padded carries state
            float ig = sigmoid_f(a0 + b0);
            float fg = sigmoid_f(a1 + b1);
            float gg = tanh_f(a2 + b2);
            float og = sigmoid_f(a3 + b3);
            c = fmaf(fg, c, ig * gg);
            h = og * tanh_f(c);
        }
        hbuf[u] = h;                   // same-wave lgkmcnt orders vs next reads

        tokc = tokn; tokn = tokf; zxc = zxn;
    }

    out[row * (2 * HID) + dir * HID + u] = h;
}

extern "C" void kernel_launch(void* const* d_in, const int* in_sizes, int n_in,
                              void* d_out, int out_size, void* d_ws, size_t ws_size,
                              hipStream_t stream) {
    const int*   tokens = (const int*)  d_in[0];
    const float* emb    = (const float*)d_in[1];
    const float* Wx_f   = (const float*)d_in[2];
    const float* Wh_f   = (const float*)d_in[3];
    const float* b_f    = (const float*)d_in[4];
    const float* Wx_b   = (const float*)d_in[5];
    const float* Wh_b   = (const float*)d_in[6];
    const float* b_b    = (const float*)d_in[7];
    float* out = (float*)d_out;

    float* zx_tab = (float*)d_ws;   // 2*1000*256*4 = 1.95 MB of d_ws

    hipLaunchKernelGGL(zx_table_kernel, dim3(2 * VOCAB), dim3(GATES), 0, stream,
                       emb, Wx_f, b_f, Wx_b, b_b, zx_tab);
    hipLaunchKernelGGL(lstm_rec_kernel, dim3(2 * B_TOT), dim3(HID), 0, stream,
                       tokens, Wh_f, Wh_b, zx_tab, out);
}

// Round 12
// 781.187 us; speedup vs baseline: 1.4716x; 1.1890x over previous
//
#include <hip/hip_runtime.h>

#define T_STEPS 1024
#define B_TOT   512
#define VOCAB   1000
#define EMB     64
#define HID     64
#define GATES   256   // 4*HID

typedef float  f32x4  __attribute__((ext_vector_type(4)));
typedef short  bf16x8 __attribute__((ext_vector_type(8)));   // 8 bf16 = 4 VGPRs

__device__ __forceinline__ float fast_rcp(float x)  { return __builtin_amdgcn_rcpf(x); }
__device__ __forceinline__ float fast_exp2(float x) { return __builtin_amdgcn_exp2f(x); }
__device__ __forceinline__ float sigmoid_f(float x) {
    return fast_rcp(1.0f + fast_exp2(-1.4426950408889634f * x));
}
__device__ __forceinline__ float tanh_f(float x) {
    float e = fast_exp2(2.8853900817779268f * x);
    return 1.0f - 2.0f * fast_rcp(e + 1.0f);
}
__device__ __forceinline__ unsigned short f2bf(float x) {   // RNE f32->bf16
    unsigned u = __float_as_uint(x);
    u = u + 0x7FFFu + ((u >> 16) & 1u);
    return (unsigned short)(u >> 16);
}
__device__ __forceinline__ float bf2f(unsigned short h) {
    return __uint_as_float(((unsigned)h) << 16);
}

// ---------------------------------------------------------------------------
// Kernel 1: zx table. zx_tab[dir][vocab][col], col = linear gate column
// (i:0-63, f:64-127, g:128-191, o:192-255). Input projection + bias folded.
// ---------------------------------------------------------------------------
__global__ __launch_bounds__(256, 4)
void zx_table_kernel(const float* __restrict__ emb,
                     const float* __restrict__ Wx_f, const float* __restrict__ b_f,
                     const float* __restrict__ Wx_b, const float* __restrict__ b_b,
                     float* __restrict__ zx_tab)
{
    const int bid = blockIdx.x;            // 0..1999
    const int dir = bid / VOCAB;
    const int v   = bid - dir * VOCAB;
    const int j   = threadIdx.x;           // gate column

    const float* __restrict__ Wx = dir ? Wx_b : Wx_f;
    const float* __restrict__ bv = dir ? b_b  : b_f;

    __shared__ float4 x4[EMB / 4];
    if (j < EMB / 4) x4[j] = ((const float4*)emb)[v * (EMB / 4) + j];
    __syncthreads();

    float a0 = bv[j], a1 = 0.f, a2 = 0.f, a3 = 0.f;
#pragma unroll
    for (int q = 0; q < EMB / 4; ++q) {
        float4 xv = x4[q];
        a0 = fmaf(xv.x, Wx[(4 * q + 0) * GATES + j], a0);
        a1 = fmaf(xv.y, Wx[(4 * q + 1) * GATES + j], a1);
        a2 = fmaf(xv.z, Wx[(4 * q + 2) * GATES + j], a2);
        a3 = fmaf(xv.w, Wx[(4 * q + 3) * GATES + j], a3);
    }
    zx_tab[(dir * VOCAB + v) * GATES + j] = (a0 + a1) + (a2 + a3);
}

// ---------------------------------------------------------------------------
// Kernel 2: Wh -> bf16 hi/lo B-fragments in MFMA fragment order.
// v_mfma_f32_16x16x32_bf16 B-layout: lane l holds B[k = 8*(l>>4)+j][n = l&15].
// Tile beta = dir*32 + g*8 + kt*4 + nt covers k in [kt*32,kt*32+32),
// n(col) in [g*64+nt*16, +16). Stored: [beta][lane][8] ushort.
// ---------------------------------------------------------------------------
__global__ __launch_bounds__(64)
void bfrag_kernel(const float* __restrict__ Wh_f, const float* __restrict__ Wh_b,
                  unsigned short* __restrict__ bhi, unsigned short* __restrict__ blo)
{
    const int beta = blockIdx.x;          // 0..63
    const int dir = beta >> 5, g = (beta >> 3) & 3, kt = (beta >> 2) & 1, nt = beta & 3;
    const int l = threadIdx.x;
    const float* __restrict__ Wh = dir ? Wh_b : Wh_f;

    bf16x8 vhi, vlo;
#pragma unroll
    for (int j = 0; j < 8; ++j) {
        int k   = kt * 32 + (l >> 4) * 8 + j;
        int col = g * 64 + nt * 16 + (l & 15);
        float wv = Wh[k * GATES + col];
        unsigned short hi = f2bf(wv);
        unsigned short lo = f2bf(wv - bf2f(hi));
        vhi[j] = (short)hi;
        vlo[j] = (short)lo;
    }
    ((bf16x8*)bhi)[beta * 64 + l] = vhi;
    ((bf16x8*)blo)[beta * 64 + l] = vlo;
}

// ---------------------------------------------------------------------------
// Kernel 3: recurrence via MFMA, split-bf16 (W=Whi+Wlo, h=hhi+hlo; drop lo*lo).
// 256 blocks = (dir, 4-row group), 4 waves. Wave g computes gate g's
// z(4 rows x 64 cols) with 24 mfma_f32_16x16x32_bf16 (rows 4-15 of A are
// hard zeros in LDS). acc is initialized from the prefetched zx float4
// (C operand). Exchange: raw z -> LDS -> update on wave w = row w
// (wave-uniform token mask) -> h split to bf16 hi/lo -> LDS (72-ushort row
// pitch => ~2-way banks on the b128 A-reads) -> next step's A-frags.
// ---------------------------------------------------------------------------
__global__ __launch_bounds__(256)
void lstm_mfma_kernel(const int* __restrict__ tokens,
                      const float* __restrict__ zx_tab,
                      const unsigned short* __restrict__ bhi,
                      const unsigned short* __restrict__ blo,
                      float* __restrict__ out)
{
    const int bid = blockIdx.x;           // 0..255
    const int dir = bid >> 7;
    const int rg  = bid & 127;
    const int tid = threadIdx.x;
    const int w   = tid >> 6;             // wave = gate for MFMA, = row for update
    const int l   = tid & 63;

    const float* __restrict__ zx = zx_tab + dir * (VOCAB * GATES);
    const int row0 = rg * 4;

    // register-resident B fragments: [kt][nt], hi and lo
    bf16x8 Bh[2][4], Bl[2][4];
#pragma unroll
    for (int kt = 0; kt < 2; ++kt)
#pragma unroll
        for (int nt = 0; nt < 4; ++nt) {
            int beta = dir * 32 + w * 8 + kt * 4 + nt;
            Bh[kt][nt] = ((const bf16x8*)bhi)[beta * 64 + l];
            Bl[kt][nt] = ((const bf16x8*)blo)[beta * 64 + l];
        }

    __shared__ unsigned short h_hi[16][72];   // rows 4-15 stay zero forever
    __shared__ unsigned short h_lo[16][72];
    __shared__ float z_lds[4][4][64];         // [gate][row][unit]

    for (int i = tid; i < 16 * 72; i += 256) {
        ((unsigned short*)h_hi)[i] = 0;
        ((unsigned short*)h_lo)[i] = 0;
    }

    float c = 0.f, h = 0.f;                   // state of (row=w, unit=l)

    const int* __restrict__ tr0 = tokens + (row0 + 0) * T_STEPS;
    const int* __restrict__ tr1 = tokens + (row0 + 1) * T_STEPS;
    const int* __restrict__ tr2 = tokens + (row0 + 2) * T_STEPS;
    const int* __restrict__ tr3 = tokens + (row0 + 3) * T_STEPS;
#define POS(t) (dir ? (T_STEPS - 1 - (t)) : (t))

    int t0c = tr0[POS(0)], t1c = tr1[POS(0)], t2c = tr2[POS(0)], t3c = tr3[POS(0)];
    int t0n = tr0[POS(1)], t1n = tr1[POS(1)], t2n = tr2[POS(1)], t3n = tr3[POS(1)];

    const int lc      = l & 15;
    const int colBase = w * 64 + lc;          // this wave's gate cols, lane col

    f32x4 zxc[4];
#pragma unroll
    for (int nt = 0; nt < 4; ++nt) {
        zxc[nt][0] = zx[t0c * GATES + colBase + nt * 16];
        zxc[nt][1] = zx[t1c * GATES + colBase + nt * 16];
        zxc[nt][2] = zx[t2c * GATES + colBase + nt * 16];
        zxc[nt][3] = zx[t3c * GATES + colBase + nt * 16];
    }
    int myTokC = (w == 0) ? t0c : (w == 1) ? t1c : (w == 2) ? t2c : t3c;
    __syncthreads();

    const int arow = l & 15;                  // A-frag row (valid rows 0-3)
    const int acg  = (l >> 4) * 8;            // A-frag k-offset within K-tile

#pragma unroll 1
    for (int t = 0; t < T_STEPS; ++t) {
        // ---- A fragments (h state of step t-1) ----
        bf16x8 Ah0 = *(const bf16x8*)&h_hi[arow][acg];
        bf16x8 Ah1 = *(const bf16x8*)&h_hi[arow][32 + acg];
        bf16x8 Al0 = *(const bf16x8*)&h_lo[arow][acg];
        bf16x8 Al1 = *(const bf16x8*)&h_lo[arow][32 + acg];

        // ---- prefetch t+2 tokens, t+1 zx (hide under MFMA/exchange) ----
        int sp2 = POS((t + 2 < T_STEPS) ? (t + 2) : (T_STEPS - 1));
        int t0f = tr0[sp2], t1f = tr1[sp2], t2f = tr2[sp2], t3f = tr3[sp2];
        f32x4 zxn[4];
#pragma unroll
        for (int nt = 0; nt < 4; ++nt) {
            zxn[nt][0] = zx[t0n * GATES + colBase + nt * 16];
            zxn[nt][1] = zx[t1n * GATES + colBase + nt * 16];
            zxn[nt][2] = zx[t2n * GATES + colBase + nt * 16];
            zxn[nt][3] = zx[t3n * GATES + colBase + nt * 16];
        }

        // ---- 24 MFMA: acc = zx + Ah*Bh + Ah*Bl + Al*Bh ----
        f32x4 acc[4] = { zxc[0], zxc[1], zxc[2], zxc[3] };
#pragma unroll
        for (int nt = 0; nt < 4; ++nt) {
            acc[nt] = __builtin_amdgcn_mfma_f32_16x16x32_bf16(Ah0, Bh[0][nt], acc[nt], 0, 0, 0);
            acc[nt] = __builtin_amdgcn_mfma_f32_16x16x32_bf16(Ah1, Bh[1][nt], acc[nt], 0, 0, 0);
            acc[nt] = __builtin_amdgcn_mfma_f32_16x16x32_bf16(Ah0, Bl[0][nt], acc[nt], 0, 0, 0);
            acc[nt] = __builtin_amdgcn_mfma_f32_16x16x32_bf16(Ah1, Bl[1][nt], acc[nt], 0, 0, 0);
            acc[nt] = __builtin_amdgcn_mfma_f32_16x16x32_bf16(Al0, Bh[0][nt], acc[nt], 0, 0, 0);
            acc[nt] = __builtin_amdgcn_mfma_f32_16x16x32_bf16(Al1, Bh[1][nt], acc[nt], 0, 0, 0);
        }

        // ---- publish raw z: lanes 0-15 hold rows 0-3 (D: row=(l>>4)*4+reg) ----
        if (l < 16) {
#pragma unroll
            for (int nt = 0; nt < 4; ++nt) {
                z_lds[w][0][nt * 16 + l] = acc[nt][0];
                z_lds[w][1][nt * 16 + l] = acc[nt][1];
                z_lds[w][2][nt * 16 + l] = acc[nt][2];
                z_lds[w][3][nt * 16 + l] = acc[nt][3];
            }
        }
        __syncthreads();

        // ---- update: thread (row=w, unit=l); token mask wave-uniform ----
        float zi = z_lds[0][w][l];
        float zf = z_lds[1][w][l];
        float zg = z_lds[2][w][l];
        float zo = z_lds[3][w][l];
        if (myTokC != 0) {                    // Keras mask_zero: carry if padded
            float ig = sigmoid_f(zi);
            float fg = sigmoid_f(zf);
            float gg = tanh_f(zg);
            float og = sigmoid_f(zo);
            c = fmaf(fg, c, ig * gg);
            h = og * tanh_f(c);
            unsigned short hh = f2bf(h);
            unsigned short hl = f2bf(h - bf2f(hh));
            h_hi[w][l] = hh;                  // stale value kept when masked
            h_lo[w][l] = hl;
        }
        __syncthreads();

        // ---- rotate prefetch ----
        t0c = t0n; t1c = t1n; t2c = t2n; t3c = t3n;
        t0n = t0f; t1n = t1f; t2n = t2f; t3n = t3f;
        zxc[0] = zxn[0]; zxc[1] = zxn[1]; zxc[2] = zxn[2]; zxc[3] = zxn[3];
        myTokC = (w == 0) ? t0c : (w == 1) ? t1c : (w == 2) ? t2c : t3c;
    }

    out[(row0 + w) * (2 * HID) + dir * HID + l] = h;
#undef POS
}

extern "C" void kernel_launch(void* const* d_in, const int* in_sizes, int n_in,
                              void* d_out, int out_size, void* d_ws, size_t ws_size,
                              hipStream_t stream) {
    const int*   tokens = (const int*)  d_in[0];
    const float* emb    = (const float*)d_in[1];
    const float* Wx_f   = (const float*)d_in[2];
    const float* Wh_f   = (const float*)d_in[3];
    const float* b_f    = (const float*)d_in[4];
    const float* Wx_b   = (const float*)d_in[5];
    const float* Wh_b   = (const float*)d_in[6];
    const float* b_b    = (const float*)d_in[7];
    float* out = (float*)d_out;

    // ws layout: zx table (2*1000*256 f32 = 2,048,000 B, 16B-aligned),
    // then bhi (65,536 B), then blo (65,536 B). Total ~2.18 MB.
    float*          zx_tab = (float*)d_ws;
    unsigned short* bhi    = (unsigned short*)((char*)d_ws + 2048000);
    unsigned short* blo    = (unsigned short*)((char*)d_ws + 2048000 + 65536);

    hipLaunchKernelGGL(zx_table_kernel, dim3(2 * VOCAB), dim3(GATES), 0, stream,
                       emb, Wx_f, b_f, Wx_b, b_b, zx_tab);
    hipLaunchKernelGGL(bfrag_kernel, dim3(64), dim3(64), 0, stream,
                       Wh_f, Wh_b, bhi, blo);
    hipLaunchKernelGGL(lstm_mfma_kernel, dim3(256), dim3(256), 0, stream,
                       tokens, zx_tab, bhi, blo, out);
}